// Round 9
// baseline (8180.397 us; speedup 1.0000x reference)
//
#include <hip/hip_runtime.h>
#include <stdint.h>

#define T_STEPS 2048
#define BATCH   64
#define IN_SZ   256
#define HID     512
#define FANG    768          // HID + IN_SZ
#define NLAYER  2
#define TOT_STEPS (T_STEPS*NLAYER)

typedef _Float16 h2 __attribute__((ext_vector_type(2)));
typedef unsigned long long u64;
typedef unsigned int u32;

__device__ __forceinline__ float dot2f(h2 a, h2 b, float c) {
#if __has_builtin(__builtin_amdgcn_fdot2)
    return __builtin_amdgcn_fdot2(a, b, c, false);
#else
    return c + (float)a.x * (float)b.x + (float)a.y * (float)b.y;
#endif
}

__device__ __forceinline__ u32 packh2(float a, float b) {
    h2 t{(_Float16)a, (_Float16)b};
    return __builtin_bit_cast(u32, t);
}
__device__ __forceinline__ h2 bch2(float v) { return __builtin_bit_cast(h2, v); }
__device__ __forceinline__ h2 bch2u(u32 v)  { return __builtin_bit_cast(h2, v); }

// Round-2/6/8-PROVEN exchange: relaxed agent-scope atomics on one u64
// (tag32 | 2xfp16). Tag and data in ONE word -> no fences needed.
__device__ __forceinline__ u64 ld_llc(const u64* p) {
    return __hip_atomic_load(p, __ATOMIC_RELAXED, __HIP_MEMORY_SCOPE_AGENT);
}
__device__ __forceinline__ void st_llc(u64* p, u64 v) {
    __hip_atomic_store(p, v, __ATOMIC_RELAXED, __HIP_MEMORY_SCOPE_AGENT);
}

// DPP quad reduce (proven): xor1 + xor2 -> every lane has its quad sum.
template<int CTRL>
__device__ __forceinline__ float dpp_add(float x) {
    int xi = __builtin_bit_cast(int, x);
    int yi = __builtin_amdgcn_update_dpp(0, xi, CTRL, 0xf, 0xf, true);
    return x + __builtin_bit_cast(float, yi);
}
__device__ __forceinline__ float reduce8(float x) {
    x = dpp_add<0xB1>(x);          // xor1
    x = dpp_add<0x4E>(x);          // xor2
    x += __shfl_xor(x, 4);         // xor4 -> full 8-lane sum in all 8 lanes
    return x;
}

// -------------------------------------------------------------------------
// Kernel 1: Xproj — persistent-B fp16 dot2 GEMM (proven). fp16-packed out.
// -------------------------------------------------------------------------
__global__ __launch_bounds__(256) void xproj_kernel(
    const float* __restrict__ input,
    const float* __restrict__ gate_w,
    const float* __restrict__ gate_b,
    u32* __restrict__ xp16)
{
    __shared__ _Float16 Bs[64][264];
    __shared__ _Float16 As[64][264];

    const int jt = blockIdx.x;         // 0..7
    const int mg = blockIdx.y;         // 0..63
    const int tid = threadIdx.x;
    const int tx = tid & 15, ty = tid >> 4;
    const int j0 = jt * 64;

    #pragma unroll
    for (int l = 0; l < 16; ++l) {
        int e = tid + l * 256;
        int i = e >> 6, kq = e & 63;
        float4 v = *(const float4*)&gate_w[(size_t)(j0 + i) * FANG + HID + kq * 4];
        *(h2*)&Bs[i][kq * 4]     = h2{(_Float16)v.x, (_Float16)v.y};
        *(h2*)&Bs[i][kq * 4 + 2] = h2{(_Float16)v.z, (_Float16)v.w};
    }

    const float4 gb = *(const float4*)&gate_b[j0 + tx * 4];

    for (int mt = 0; mt < 32; ++mt) {
        const int m0 = (mg * 32 + mt) * 64;
        __syncthreads();
        #pragma unroll
        for (int l = 0; l < 16; ++l) {
            int e = tid + l * 256;
            int i = e >> 6, kq = e & 63;
            float4 v = *(const float4*)&input[(size_t)(m0 + i) * IN_SZ + kq * 4];
            *(h2*)&As[i][kq * 4]     = h2{(_Float16)v.x, (_Float16)v.y};
            *(h2*)&As[i][kq * 4 + 2] = h2{(_Float16)v.z, (_Float16)v.w};
        }
        __syncthreads();

        float acc[4][4] = {};
        #pragma unroll
        for (int q = 0; q < 32; ++q) {
            const int k = ((q + tx) & 31) * 8;
            float4 av[4], bv[4];
            #pragma unroll
            for (int i = 0; i < 4; ++i)  av[i] = *(const float4*)&As[ty * 4 + i][k];
            #pragma unroll
            for (int jj = 0; jj < 4; ++jj) bv[jj] = *(const float4*)&Bs[tx * 4 + jj][k];
            #pragma unroll
            for (int i = 0; i < 4; ++i) {
                h2 a0 = bch2(av[i].x), a1 = bch2(av[i].y);
                h2 a2 = bch2(av[i].z), a3 = bch2(av[i].w);
                #pragma unroll
                for (int jj = 0; jj < 4; ++jj) {
                    acc[i][jj] = dot2f(a0, bch2(bv[jj].x), acc[i][jj]);
                    acc[i][jj] = dot2f(a1, bch2(bv[jj].y), acc[i][jj]);
                    acc[i][jj] = dot2f(a2, bch2(bv[jj].z), acc[i][jj]);
                    acc[i][jj] = dot2f(a3, bch2(bv[jj].w), acc[i][jj]);
                }
            }
        }

        #pragma unroll
        for (int i = 0; i < 4; ++i) {
            uint2 ww = { packh2(acc[i][0] + gb.x, acc[i][1] + gb.y),
                         packh2(acc[i][2] + gb.z, acc[i][3] + gb.w) };
            *(uint2*)&xp16[(size_t)(m0 + ty * 4 + i) * 256 + ((j0 + tx * 4) >> 1)] = ww;
        }
    }
}

// -------------------------------------------------------------------------
// Kernel 2: recurrence. 128 WGs = 2 slices x 64 batch, 1024 threads (16
// waves, 4/SIMD -> 128-reg budget, weights in PURE ARCH VGPRs, no AGPRs).
// Thread (g = tid>>3, c = tid&7): row pair j0 = s*256 + g*2, k-cols =
// own-slice [s*256 + c*32, +32) + remote [(1-s)*256 + c*32, +32)
// => 64 h2 weights in VGPRs (~110 total regs < 128).
// Per step: probe remote -> bar1 -> own-half dot (hides LLC RT) ->
// detect+stage remote -> bar2 -> remote-half dot -> 8-lane reduce -> act.
// h exchange: hx[2][64][256] u64 (tag|2xfp16), single remote producer
// (round-8-proven back-pressure chain). LDS h: stride-20 chunks (16 chunks
// x 20 words): 8 per-wave broadcast streams on disjoint bank quads, 16B
// aligned for b128.
// -------------------------------------------------------------------------
__global__ __launch_bounds__(1024, 4) void lstm_kernel(
    const float* __restrict__ gate_w,
    const u32* __restrict__ xp16,
    u64* __restrict__ hx)
{
    const int blk = blockIdx.x;     // 0..127
    const int s   = blk >> 6;       // slice 0..1
    const int b   = blk & 63;       // batch row
    const int tid = threadIdx.x;    // 0..1023
    const int g   = tid >> 3;       // row-pair 0..127
    const int c   = tid & 7;        // k-eighth
    const int j0  = s * 256 + g * 2;

    __shared__ u32 hbuf[2][320];    // 16 chunks x 20-word stride

    // weights: w2[p*32 + q*8 + m*2 + r]; p=0 own half, p=1 remote half;
    // q = float4 group (0..3), m = word in group (0..3), r = row (0..1)
    h2 w2[64];
    #pragma unroll
    for (int p = 0; p < 2; ++p) {
        const int kb = (p == 0 ? s : 1 - s) * 256 + c * 32;
        #pragma unroll
        for (int r = 0; r < 2; ++r) {
            const float* wr = gate_w + (size_t)(j0 + r) * FANG + kb;
            #pragma unroll
            for (int f = 0; f < 8; ++f) {
                float4 v = *(const float4*)(wr + f * 4);
                const int w0 = 2 * f, w1 = 2 * f + 1;
                w2[p * 32 + (w0 >> 2) * 8 + (w0 & 3) * 2 + r] = h2{(_Float16)v.x, (_Float16)v.y};
                w2[p * 32 + (w1 >> 2) * 8 + (w1 & 3) * 2 + r] = h2{(_Float16)v.z, (_Float16)v.w};
            }
        }
    }

    // LDS addresses (logical h2-word w at (w>>4)*20 + (w&15))
    const int cb_own = (s * 8 + c) * 20;                       // own-half read base
    const int cb_rem = ((1 - s) * 8 + c) * 20;                 // remote-half read base
    const int prw    = (1 - s) * 128 + tid;                    // polled remote word (tid<128)
    const int plds   = ((1 - s) * 8 + (tid >> 4)) * 20 + (tid & 15);
    const int blds   = (s * 8 + (g >> 4)) * 20 + (g & 15);     // bypass word addr

    if (tid < 320) hbuf[0][tid] = 0;   // h = 0 for step 0 (hx memset'd too)

    float cv0 = 0.f, cv1 = 0.f;        // cell state (c==0 lanes, row pair)

    for (int st = 0; st < TOT_STEPS; ++st) {
        const int t   = st & (T_STEPS - 1);
        const int buf = st & 1;

        // xproj word for this act-lane's row pair (in flight during step)
        u32 xw = 0;
        if (c == 0) xw = xp16[((size_t)t * BATCH + b) * 256 + s * 128 + g];

        // first probe of the remote word, in flight during own-half dot
        const u64* pp = hx + ((size_t)buf * BATCH + b) * 256 + prw;
        u64 pv = 0;
        if (tid < 128) pv = ld_llc(pp);

        __syncthreads();   // bar1: last step's bypass (own-slice h) published

        // ---- own-half dot (local data, hides the LLC round trip) ----
        float a0 = 0.f, a1 = 0.f;
        {
            const u32* hb = &hbuf[buf][cb_own];
            #pragma unroll
            for (int q = 0; q < 4; ++q) {
                float4 rv = *(const float4*)(hb + q * 4);
                h2 x0 = bch2(rv.x), x1 = bch2(rv.y), x2 = bch2(rv.z), x3 = bch2(rv.w);
                a0 = dot2f(w2[q*8+0], x0, a0); a1 = dot2f(w2[q*8+1], x0, a1);
                a0 = dot2f(w2[q*8+2], x1, a0); a1 = dot2f(w2[q*8+3], x1, a1);
                a0 = dot2f(w2[q*8+4], x2, a0); a1 = dot2f(w2[q*8+5], x2, a1);
                a0 = dot2f(w2[q*8+6], x3, a0); a1 = dot2f(w2[q*8+7], x3, a1);
            }
        }

        // ---- detect + stage the remote slice (single producer) ----
        if (tid < 128) {
            u64 v = pv;
            int spin = 0;
            while ((u32)(v >> 32) != (u32)st) {
                v = ld_llc(pp);
                if (++spin > (1 << 16)) break;        // safety bailout
                if (spin > 64) __builtin_amdgcn_s_sleep(1);
            }
            hbuf[buf][plds] = (u32)v;
        }
        __syncthreads();   // bar2: remote h staged

        // ---- remote-half dot ----
        {
            const u32* hb = &hbuf[buf][cb_rem];
            #pragma unroll
            for (int q = 0; q < 4; ++q) {
                float4 rv = *(const float4*)(hb + q * 4);
                h2 x0 = bch2(rv.x), x1 = bch2(rv.y), x2 = bch2(rv.z), x3 = bch2(rv.w);
                a0 = dot2f(w2[32+q*8+0], x0, a0); a1 = dot2f(w2[32+q*8+1], x0, a1);
                a0 = dot2f(w2[32+q*8+2], x1, a0); a1 = dot2f(w2[32+q*8+3], x1, a1);
                a0 = dot2f(w2[32+q*8+4], x2, a0); a1 = dot2f(w2[32+q*8+5], x2, a1);
                a0 = dot2f(w2[32+q*8+6], x3, a0); a1 = dot2f(w2[32+q*8+7], x3, a1);
            }
        }

        // 8-lane reduce across the k-eighth lanes
        a0 = reduce8(a0);
        a1 = reduce8(a1);

        if (c == 0) {
            h2 xp = bch2u(xw);
            float hf0, hf1;
            {
                float gg = a0 + (float)xp.x;
                gg = fminf(fmaxf(gg, -30.0f), 30.0f);
                float sg = 1.0f / (1.0f + __expf(-gg));
                float e2 = __expf(2.0f * gg);
                float ch = (e2 - 1.0f) / (e2 + 1.0f);
                cv0 = cv0 * sg + ch * sg;
                float ca = fminf(fmaxf(cv0, -15.0f), 15.0f);
                float e3 = __expf(2.0f * ca);
                hf0 = ((e3 - 1.0f) / (e3 + 1.0f)) * sg;
            }
            {
                float gg = a1 + (float)xp.y;
                gg = fminf(fmaxf(gg, -30.0f), 30.0f);
                float sg = 1.0f / (1.0f + __expf(-gg));
                float e2 = __expf(2.0f * gg);
                float ch = (e2 - 1.0f) / (e2 + 1.0f);
                cv1 = cv1 * sg + ch * sg;
                float ca = fminf(fmaxf(cv1, -15.0f), 15.0f);
                float e3 = __expf(2.0f * ca);
                hf1 = ((e3 - 1.0f) / (e3 + 1.0f)) * sg;
            }
            u32 pk = packh2(hf0, hf1);
            // publish to the remote WG (tagged word) + local bypass to LDS
            st_llc(hx + ((size_t)((st + 1) & 1) * BATCH + b) * 256 + s * 128 + g,
                   (u64)pk | ((u64)(u32)(st + 1) << 32));
            hbuf[buf ^ 1][blds] = pk;
        }
        // no trailing barrier: bypass writes hbuf[buf^1]; bar1 of the next
        // step orders them before any read (pollers of step st+1 write only
        // remote words of hbuf[buf^1], disjoint from the bypass's own words).
    }
}

// -------------------------------------------------------------------------
// Kernel 3: output = h_final @ out_w.T + out_b. Final h in hx buffer 0
// (TOT_STEPS even), 2 fp16 per word's low 32 bits.
// -------------------------------------------------------------------------
__global__ __launch_bounds__(256) void out_kernel(
    const u64* __restrict__ hx,
    const float* __restrict__ out_w,
    const float* __restrict__ out_b,
    float* __restrict__ out)
{
    const int b  = blockIdx.x;    // 64
    const int jt = threadIdx.x;   // 256
    __shared__ float hrow[512];

    {
        u64 v = hx[(size_t)b * 256 + jt];
        h2 pr = bch2u((u32)v);
        hrow[2 * jt]     = (float)pr.x;
        hrow[2 * jt + 1] = (float)pr.y;
    }
    __syncthreads();

    float acc = out_b[jt];
    const float* wr = out_w + (size_t)jt * HID;
    #pragma unroll 8
    for (int k = 0; k < HID; ++k)
        acc += hrow[k] * wr[k];
    out[(size_t)b * IN_SZ + jt] = acc;
}

// -------------------------------------------------------------------------
extern "C" void kernel_launch(void* const* d_in, const int* in_sizes, int n_in,
                              void* d_out, int out_size, void* d_ws, size_t ws_size,
                              hipStream_t stream)
{
    const float* input  = (const float*)d_in[0];
    const float* gate_w = (const float*)d_in[1];
    const float* gate_b = (const float*)d_in[2];
    const float* out_w  = (const float*)d_in[3];
    const float* out_b  = (const float*)d_in[4];
    float* out = (float*)d_out;

    // ws layout: Xproj fp16-packed (128 MB) | hx [2][64][256] u64 (256 KB)
    u32* xp16 = (u32*)d_ws;
    const size_t xbytes = (size_t)T_STEPS * BATCH * 256 * sizeof(u32);
    u64* hx = (u64*)((char*)d_ws + xbytes);

    // zero the exchange every launch: tag 0 == initial h = 0; graph replays
    // must never see stale tags.
    (void)hipMemsetAsync(hx, 0, (size_t)2 * BATCH * 256 * sizeof(u64), stream);

    dim3 g1(8, 64);
    xproj_kernel<<<g1, 256, 0, stream>>>(input, gate_w, gate_b, xp16);
    lstm_kernel<<<128, 1024, 0, stream>>>(gate_w, xp16, hx);
    out_kernel<<<64, 256, 0, stream>>>(hx, out_w, out_b, out);
}

// Round 10
// 5073.228 us; speedup vs baseline: 1.6125x; 1.6125x over previous
//
#include <hip/hip_runtime.h>
#include <stdint.h>

#define T_STEPS 2048
#define BATCH   64
#define IN_SZ   256
#define HID     512
#define FANG    768          // HID + IN_SZ
#define NLAYER  2
#define TOT_STEPS (T_STEPS*NLAYER)

typedef _Float16 h2 __attribute__((ext_vector_type(2)));
typedef unsigned long long u64;
typedef unsigned int u32;

__device__ __forceinline__ float dot2f(h2 a, h2 b, float c) {
#if __has_builtin(__builtin_amdgcn_fdot2)
    return __builtin_amdgcn_fdot2(a, b, c, false);
#else
    return c + (float)a.x * (float)b.x + (float)a.y * (float)b.y;
#endif
}

__device__ __forceinline__ u32 packh2(float a, float b) {
    h2 t{(_Float16)a, (_Float16)b};
    return __builtin_bit_cast(u32, t);
}
__device__ __forceinline__ h2 bch2(float v) { return __builtin_bit_cast(h2, v); }
__device__ __forceinline__ h2 bch2u(u32 v)  { return __builtin_bit_cast(h2, v); }

// Round-2/6/8-PROVEN exchange: relaxed agent-scope atomics on one u64
// (tag32 | 2xfp16). Tag and data in ONE word -> no fences needed.
__device__ __forceinline__ u64 ld_llc(const u64* p) {
    return __hip_atomic_load(p, __ATOMIC_RELAXED, __HIP_MEMORY_SCOPE_AGENT);
}
__device__ __forceinline__ void st_llc(u64* p, u64 v) {
    __hip_atomic_store(p, v, __ATOMIC_RELAXED, __HIP_MEMORY_SCOPE_AGENT);
}

// DPP quad reduce (proven): xor1 + xor2 -> every lane has its quad sum.
template<int CTRL>
__device__ __forceinline__ float dpp_add(float x) {
    int xi = __builtin_bit_cast(int, x);
    int yi = __builtin_amdgcn_update_dpp(0, xi, CTRL, 0xf, 0xf, true);
    return x + __builtin_bit_cast(float, yi);
}
__device__ __forceinline__ float reduce4(float x) {
    x = dpp_add<0xB1>(x);          // quad xor1
    x = dpp_add<0x4E>(x);          // quad xor2
    return x;
}

// -------------------------------------------------------------------------
// Kernel 1: Xproj — persistent-B fp16 dot2 GEMM (proven). fp16-packed out.
// -------------------------------------------------------------------------
__global__ __launch_bounds__(256) void xproj_kernel(
    const float* __restrict__ input,
    const float* __restrict__ gate_w,
    const float* __restrict__ gate_b,
    u32* __restrict__ xp16)
{
    __shared__ _Float16 Bs[64][264];
    __shared__ _Float16 As[64][264];

    const int jt = blockIdx.x;         // 0..7
    const int mg = blockIdx.y;         // 0..63
    const int tid = threadIdx.x;
    const int tx = tid & 15, ty = tid >> 4;
    const int j0 = jt * 64;

    #pragma unroll
    for (int l = 0; l < 16; ++l) {
        int e = tid + l * 256;
        int i = e >> 6, kq = e & 63;
        float4 v = *(const float4*)&gate_w[(size_t)(j0 + i) * FANG + HID + kq * 4];
        *(h2*)&Bs[i][kq * 4]     = h2{(_Float16)v.x, (_Float16)v.y};
        *(h2*)&Bs[i][kq * 4 + 2] = h2{(_Float16)v.z, (_Float16)v.w};
    }

    const float4 gb = *(const float4*)&gate_b[j0 + tx * 4];

    for (int mt = 0; mt < 32; ++mt) {
        const int m0 = (mg * 32 + mt) * 64;
        __syncthreads();
        #pragma unroll
        for (int l = 0; l < 16; ++l) {
            int e = tid + l * 256;
            int i = e >> 6, kq = e & 63;
            float4 v = *(const float4*)&input[(size_t)(m0 + i) * IN_SZ + kq * 4];
            *(h2*)&As[i][kq * 4]     = h2{(_Float16)v.x, (_Float16)v.y};
            *(h2*)&As[i][kq * 4 + 2] = h2{(_Float16)v.z, (_Float16)v.w};
        }
        __syncthreads();

        float acc[4][4] = {};
        #pragma unroll
        for (int q = 0; q < 32; ++q) {
            const int k = ((q + tx) & 31) * 8;
            float4 av[4], bv[4];
            #pragma unroll
            for (int i = 0; i < 4; ++i)  av[i] = *(const float4*)&As[ty * 4 + i][k];
            #pragma unroll
            for (int jj = 0; jj < 4; ++jj) bv[jj] = *(const float4*)&Bs[tx * 4 + jj][k];
            #pragma unroll
            for (int i = 0; i < 4; ++i) {
                h2 a0 = bch2(av[i].x), a1 = bch2(av[i].y);
                h2 a2 = bch2(av[i].z), a3 = bch2(av[i].w);
                #pragma unroll
                for (int jj = 0; jj < 4; ++jj) {
                    acc[i][jj] = dot2f(a0, bch2(bv[jj].x), acc[i][jj]);
                    acc[i][jj] = dot2f(a1, bch2(bv[jj].y), acc[i][jj]);
                    acc[i][jj] = dot2f(a2, bch2(bv[jj].z), acc[i][jj]);
                    acc[i][jj] = dot2f(a3, bch2(bv[jj].w), acc[i][jj]);
                }
            }
        }

        #pragma unroll
        for (int i = 0; i < 4; ++i) {
            uint2 ww = { packh2(acc[i][0] + gb.x, acc[i][1] + gb.y),
                         packh2(acc[i][2] + gb.z, acc[i][3] + gb.w) };
            *(uint2*)&xp16[(size_t)(m0 + ty * 4 + i) * 256 + ((j0 + tx * 4) >> 1)] = ww;
        }
    }
}

// -------------------------------------------------------------------------
// Kernel 2: recurrence. 256 WGs = 4 slices x 64 batch, 512 threads, 1/CU.
// Thread (r = tid>>2, c = tid&3): ONE row j = s*128 + r, k-quarter
// [c*128, c*128+128) = 64 h2 weights -> ~104 regs, UNDER the 128-arch cap
// of the (512,2) budget split => pure arch VGPRs, no AGPR spill (the
// round-7/8/9 disease). Weight order is rotated by s (own-slice words
// first) with compile-time indices only.
// Per step: probe (tid<192) -> bar1 -> own-slice dot (u=0..3, hides RT) ->
// detect+stage remote -> bar2 -> remote dot (u=4..15) -> DPP reduce4 ->
// act (c==0, one row) -> pack pair via shfl_down(4) -> tagged store + LDS
// bypass. h exchange: hx[2][64][256] u64 (tag|2xfp16), proven chain.
// LDS: addr(w) = w; per-wave reads are 4-address broadcasts (c*64-word
// chunks) -> conflict-free (r8-verified pattern).
// -------------------------------------------------------------------------
__global__ __launch_bounds__(512, 2) void lstm_kernel(
    const float* __restrict__ gate_w,
    const u32* __restrict__ xp16,
    u64* __restrict__ hx)
{
    const int blk = blockIdx.x;     // 0..255
    const int s   = blk >> 6;       // slice 0..3 (owns rows s*128..+128)
    const int b   = blk & 63;       // batch row
    const int tid = threadIdx.x;    // 0..511
    const int r   = tid >> 2;       // row within slice 0..127
    const int c   = tid & 3;        // k-quarter lane
    const int j   = s * 128 + r;    // global row

    __shared__ u32 hl[2][264];      // h words, addr(w) = w (256 + pad)

    // weights, own-slice-first rotation: w2[u*4+m] covers h2-word
    // w(u,m) = ((s*4 + u) & 15) * 16 + c*4 + m   (u,m compile-time indexed)
    h2 w2[64];
    #pragma unroll
    for (int u = 0; u < 16; ++u) {
        const int q = (s * 4 + u) & 15;
        const float* wr = gate_w + (size_t)j * FANG + (q * 16 + c * 4) * 2;
        float4 v0 = *(const float4*)(wr);
        float4 v1 = *(const float4*)(wr + 4);
        w2[u * 4 + 0] = h2{(_Float16)v0.x, (_Float16)v0.y};
        w2[u * 4 + 1] = h2{(_Float16)v0.z, (_Float16)v0.w};
        w2[u * 4 + 2] = h2{(_Float16)v1.x, (_Float16)v1.y};
        w2[u * 4 + 3] = h2{(_Float16)v1.z, (_Float16)v1.w};
    }

    // poller mapping (tid<192): remote slices only
    const int si  = tid >> 6;                 // 0..2
    const int qs  = si + (si >= s);           // skip own slice
    const int prw = qs * 64 + (tid & 63);     // polled word = LDS addr

    if (tid < 264) hl[0][tid] = 0;            // h = 0 for step 0

    float cval = 0.0f;                        // cell state (c==0 lanes)

    for (int st = 0; st < TOT_STEPS; ++st) {
        const int t   = st & (T_STEPS - 1);
        const int buf = st & 1;

        // xproj half-word for this row (c==0 lanes; in flight during step)
        u32 xw = 0;
        if (c == 0) xw = xp16[((size_t)t * BATCH + b) * 256 + s * 64 + (r >> 1)];

        // first probe of the remote word, in flight during own-slice dot
        const u64* pp = hx + ((size_t)buf * BATCH + b) * 256 + prw;
        u64 pv = 0;
        if (tid < 192) pv = ld_llc(pp);

        __syncthreads();   // bar1: last step's bypass (own-slice h) published

        // ---- own-slice dot (u = 0..3; local data, hides the LLC RT) ----
        float p0 = 0.f, p1 = 0.f, p2 = 0.f, p3 = 0.f;
        #pragma unroll
        for (int u = 0; u < 4; ++u) {
            const int q = s * 4 + u;                       // no wrap: s*4+3 <= 15
            float4 rv = *(const float4*)&hl[buf][q * 16 + c * 4];
            p0 = dot2f(w2[u * 4 + 0], bch2(rv.x), p0);
            p1 = dot2f(w2[u * 4 + 1], bch2(rv.y), p1);
            p2 = dot2f(w2[u * 4 + 2], bch2(rv.z), p2);
            p3 = dot2f(w2[u * 4 + 3], bch2(rv.w), p3);
        }

        // ---- detect + stage the remote slices ----
        if (tid < 192) {
            u64 v = pv;
            int spin = 0;
            while ((u32)(v >> 32) != (u32)st) {
                v = ld_llc(pp);
                if (++spin > (1 << 16)) break;        // safety bailout
                if (spin > 64) __builtin_amdgcn_s_sleep(1);
            }
            hl[buf][prw] = (u32)v;
        }
        __syncthreads();   // bar2: remote h staged

        // ---- remote dot (u = 4..15) ----
        #pragma unroll
        for (int u = 4; u < 16; ++u) {
            const int q = (s * 4 + u) & 15;
            float4 rv = *(const float4*)&hl[buf][q * 16 + c * 4];
            p0 = dot2f(w2[u * 4 + 0], bch2(rv.x), p0);
            p1 = dot2f(w2[u * 4 + 1], bch2(rv.y), p1);
            p2 = dot2f(w2[u * 4 + 2], bch2(rv.z), p2);
            p3 = dot2f(w2[u * 4 + 3], bch2(rv.w), p3);
        }
        float p = (p0 + p1) + (p2 + p3);
        p = reduce4(p);                    // 4 k-lanes, DPP only

        float hf = 0.0f;
        if (c == 0) {
            h2 xp = bch2u(xw);
            float gg = p + (float)((r & 1) ? xp.y : xp.x);
            gg = fminf(fmaxf(gg, -30.0f), 30.0f);
            float sg = 1.0f / (1.0f + __expf(-gg));     // sigmoid
            float e2 = __expf(2.0f * gg);               // tanh(g)
            float ch = (e2 - 1.0f) / (e2 + 1.0f);
            cval = cval * sg + ch * sg;
            float ca = fminf(fmaxf(cval, -15.0f), 15.0f);
            float e3 = __expf(2.0f * ca);               // tanh(c)
            hf = ((e3 - 1.0f) / (e3 + 1.0f)) * sg;
        }
        // pack row pair (2m, 2m+1): odd-row owner is 4 lanes up, same wave
        float hfo = __shfl_down(hf, 4);
        if ((tid & 7) == 0) {
            const int w = s * 64 + (r >> 1);
            u32 pk = packh2(hf, hfo);
            st_llc(hx + ((size_t)((st + 1) & 1) * BATCH + b) * 256 + w,
                   (u64)pk | ((u64)(u32)(st + 1) << 32));
            hl[buf ^ 1][w] = pk;           // local bypass for own slice
        }
        // no trailing barrier: bypass writes hl[buf^1]; next step's bar1
        // orders them before any read (next pollers write only remote words).
    }
}

// -------------------------------------------------------------------------
// Kernel 3: output = h_final @ out_w.T + out_b. Final h in hx buffer 0
// (TOT_STEPS even), 2 fp16 per word's low 32 bits.
// -------------------------------------------------------------------------
__global__ __launch_bounds__(256) void out_kernel(
    const u64* __restrict__ hx,
    const float* __restrict__ out_w,
    const float* __restrict__ out_b,
    float* __restrict__ out)
{
    const int b  = blockIdx.x;    // 64
    const int jt = threadIdx.x;   // 256
    __shared__ float hrow[512];

    {
        u64 v = hx[(size_t)b * 256 + jt];
        h2 pr = bch2u((u32)v);
        hrow[2 * jt]     = (float)pr.x;
        hrow[2 * jt + 1] = (float)pr.y;
    }
    __syncthreads();

    float acc = out_b[jt];
    const float* wr = out_w + (size_t)jt * HID;
    #pragma unroll 8
    for (int k = 0; k < HID; ++k)
        acc += hrow[k] * wr[k];
    out[(size_t)b * IN_SZ + jt] = acc;
}

// -------------------------------------------------------------------------
extern "C" void kernel_launch(void* const* d_in, const int* in_sizes, int n_in,
                              void* d_out, int out_size, void* d_ws, size_t ws_size,
                              hipStream_t stream)
{
    const float* input  = (const float*)d_in[0];
    const float* gate_w = (const float*)d_in[1];
    const float* gate_b = (const float*)d_in[2];
    const float* out_w  = (const float*)d_in[3];
    const float* out_b  = (const float*)d_in[4];
    float* out = (float*)d_out;

    // ws layout: Xproj fp16-packed (128 MB) | hx [2][64][256] u64 (256 KB)
    u32* xp16 = (u32*)d_ws;
    const size_t xbytes = (size_t)T_STEPS * BATCH * 256 * sizeof(u32);
    u64* hx = (u64*)((char*)d_ws + xbytes);

    // zero the exchange every launch: tag 0 == initial h = 0; graph replays
    // must never see stale tags.
    (void)hipMemsetAsync(hx, 0, (size_t)2 * BATCH * 256 * sizeof(u64), stream);

    dim3 g1(8, 64);
    xproj_kernel<<<g1, 256, 0, stream>>>(input, gate_w, gate_b, xp16);
    lstm_kernel<<<256, 512, 0, stream>>>(gate_w, xp16, hx);
    out_kernel<<<64, 256, 0, stream>>>(hx, out_w, out_b, out);
}

// Round 11
// 4936.487 us; speedup vs baseline: 1.6571x; 1.0277x over previous
//
#include <hip/hip_runtime.h>
#include <stdint.h>

#define T_STEPS 2048
#define BATCH   64
#define IN_SZ   256
#define HID     512
#define FANG    768          // HID + IN_SZ
#define NLAYER  2
#define TOT_STEPS (T_STEPS*NLAYER)

typedef _Float16 h2 __attribute__((ext_vector_type(2)));
typedef unsigned long long u64;
typedef unsigned int u32;

__device__ __forceinline__ float dot2f(h2 a, h2 b, float c) {
#if __has_builtin(__builtin_amdgcn_fdot2)
    return __builtin_amdgcn_fdot2(a, b, c, false);
#else
    return c + (float)a.x * (float)b.x + (float)a.y * (float)b.y;
#endif
}

__device__ __forceinline__ u32 packh2(float a, float b) {
    h2 t{(_Float16)a, (_Float16)b};
    return __builtin_bit_cast(u32, t);
}
__device__ __forceinline__ h2 bch2(float v) { return __builtin_bit_cast(h2, v); }
__device__ __forceinline__ h2 bch2u(u32 v)  { return __builtin_bit_cast(h2, v); }

// Round-2/6/8/10-PROVEN exchange: relaxed agent-scope atomics on one u64
// (tag32 | 2xfp16). Tag and data in ONE word -> no fences needed.
__device__ __forceinline__ u64 ld_llc(const u64* p) {
    return __hip_atomic_load(p, __ATOMIC_RELAXED, __HIP_MEMORY_SCOPE_AGENT);
}
__device__ __forceinline__ void st_llc(u64* p, u64 v) {
    __hip_atomic_store(p, v, __ATOMIC_RELAXED, __HIP_MEMORY_SCOPE_AGENT);
}

// DPP adds (compile-time ctrl). 16-lane reduce chain (r6-proven):
// xor1, xor2 (quad sums) then row_ror:4, row_ror:8 -- lanes 0..3 (mod 16)
// end up with the full 16-lane sum. Our act lanes are c<4, i.e. exactly
// lanes 0..3 mod 16.
template<int CTRL>
__device__ __forceinline__ float dpp_add(float x) {
    int xi = __builtin_bit_cast(int, x);
    int yi = __builtin_amdgcn_update_dpp(0, xi, CTRL, 0xf, 0xf, true);
    return x + __builtin_bit_cast(float, yi);
}
__device__ __forceinline__ float reduce16(float x) {
    x = dpp_add<0xB1>(x);          // quad xor1
    x = dpp_add<0x4E>(x);          // quad xor2
    x = dpp_add<0x124>(x);         // row_ror:4
    x = dpp_add<0x128>(x);         // row_ror:8
    return x;
}

// -------------------------------------------------------------------------
// Kernel 1: Xproj — persistent-B fp16 dot2 GEMM (proven). fp16-packed out.
// -------------------------------------------------------------------------
__global__ __launch_bounds__(256) void xproj_kernel(
    const float* __restrict__ input,
    const float* __restrict__ gate_w,
    const float* __restrict__ gate_b,
    u32* __restrict__ xp16)
{
    __shared__ _Float16 Bs[64][264];
    __shared__ _Float16 As[64][264];

    const int jt = blockIdx.x;         // 0..7
    const int mg = blockIdx.y;         // 0..63
    const int tid = threadIdx.x;
    const int tx = tid & 15, ty = tid >> 4;
    const int j0 = jt * 64;

    #pragma unroll
    for (int l = 0; l < 16; ++l) {
        int e = tid + l * 256;
        int i = e >> 6, kq = e & 63;
        float4 v = *(const float4*)&gate_w[(size_t)(j0 + i) * FANG + HID + kq * 4];
        *(h2*)&Bs[i][kq * 4]     = h2{(_Float16)v.x, (_Float16)v.y};
        *(h2*)&Bs[i][kq * 4 + 2] = h2{(_Float16)v.z, (_Float16)v.w};
    }

    const float4 gb = *(const float4*)&gate_b[j0 + tx * 4];

    for (int mt = 0; mt < 32; ++mt) {
        const int m0 = (mg * 32 + mt) * 64;
        __syncthreads();
        #pragma unroll
        for (int l = 0; l < 16; ++l) {
            int e = tid + l * 256;
            int i = e >> 6, kq = e & 63;
            float4 v = *(const float4*)&input[(size_t)(m0 + i) * IN_SZ + kq * 4];
            *(h2*)&As[i][kq * 4]     = h2{(_Float16)v.x, (_Float16)v.y};
            *(h2*)&As[i][kq * 4 + 2] = h2{(_Float16)v.z, (_Float16)v.w};
        }
        __syncthreads();

        float acc[4][4] = {};
        #pragma unroll
        for (int q = 0; q < 32; ++q) {
            const int k = ((q + tx) & 31) * 8;
            float4 av[4], bv[4];
            #pragma unroll
            for (int i = 0; i < 4; ++i)  av[i] = *(const float4*)&As[ty * 4 + i][k];
            #pragma unroll
            for (int jj = 0; jj < 4; ++jj) bv[jj] = *(const float4*)&Bs[tx * 4 + jj][k];
            #pragma unroll
            for (int i = 0; i < 4; ++i) {
                h2 a0 = bch2(av[i].x), a1 = bch2(av[i].y);
                h2 a2 = bch2(av[i].z), a3 = bch2(av[i].w);
                #pragma unroll
                for (int jj = 0; jj < 4; ++jj) {
                    acc[i][jj] = dot2f(a0, bch2(bv[jj].x), acc[i][jj]);
                    acc[i][jj] = dot2f(a1, bch2(bv[jj].y), acc[i][jj]);
                    acc[i][jj] = dot2f(a2, bch2(bv[jj].z), acc[i][jj]);
                    acc[i][jj] = dot2f(a3, bch2(bv[jj].w), acc[i][jj]);
                }
            }
        }

        #pragma unroll
        for (int i = 0; i < 4; ++i) {
            uint2 ww = { packh2(acc[i][0] + gb.x, acc[i][1] + gb.y),
                         packh2(acc[i][2] + gb.z, acc[i][3] + gb.w) };
            *(uint2*)&xp16[(size_t)(m0 + ty * 4 + i) * 256 + ((j0 + tx * 4) >> 1)] = ww;
        }
    }
}

// -------------------------------------------------------------------------
// Kernel 2: recurrence. 256 WGs = 4 slices x 64 batch, 512 threads, 1/CU.
// 4-ROW REUSE: thread (g = tid>>4, c = tid&15) owns rows s*128+g*4..+3 and,
// from EACH slice q, h2-words q*64 + c*4 .. +4. Per step: 4 ds_read_b128
// (1 own + 3 remote), each feeding 16 dot2 -> LDS pipe 32 instr/CU/step
// (~384cy, was 1536 in r10). Weights 64 h2 (~95 regs < 128-arch cap).
// Own/remote split has zero divergence (every lane has exactly 1 own read).
// Per step: probe (tid<192) -> bar1 -> own-slice dot -> detect+stage ->
// bar2 -> remote dot -> DPP reduce16 -> act on lanes c<4 (one row each) ->
// pack pair (shfl_down 1) -> tagged store + LDS bypass.
// Exchange/back-pressure chain identical to r10 (proven).
// LDS: linear addr(w)=w; all reads 2-addresses-per-bank-quad (free, m136);
// poller writes 64 consecutive words (conflict-free).
// -------------------------------------------------------------------------
__global__ __launch_bounds__(512, 2) void lstm_kernel(
    const float* __restrict__ gate_w,
    const u32* __restrict__ xp16,
    u64* __restrict__ hx)
{
    const int blk = blockIdx.x;     // 0..255
    const int s   = blk >> 6;       // slice 0..3 (owns rows s*128..+128)
    const int b   = blk & 63;       // batch row
    const int tid = threadIdx.x;    // 0..511
    const int g   = tid >> 4;       // row group 0..31 (rows g*4..+3 of slice)
    const int c   = tid & 15;       // k-lane
    const int j0  = s * 128 + g * 4;

    __shared__ u32 hl[2][256];      // h words, addr(w) = w, double-buffered

    // weights: w2[rr*16 + u*4 + m] <-> h2-word ((s+u)&3)*64 + c*4 + m
    // (u = slice in own-first rotation; rr, u, m compile-time indexed)
    h2 w2[64];
    #pragma unroll
    for (int u = 0; u < 4; ++u) {
        const int kb = (((s + u) & 3) * 64 + c * 4) * 2;   // h-value index
        #pragma unroll
        for (int rr = 0; rr < 4; ++rr) {
            const float* wr = gate_w + (size_t)(j0 + rr) * FANG + kb;
            float4 v0 = *(const float4*)(wr);
            float4 v1 = *(const float4*)(wr + 4);
            w2[rr * 16 + u * 4 + 0] = h2{(_Float16)v0.x, (_Float16)v0.y};
            w2[rr * 16 + u * 4 + 1] = h2{(_Float16)v0.z, (_Float16)v0.w};
            w2[rr * 16 + u * 4 + 2] = h2{(_Float16)v1.x, (_Float16)v1.y};
            w2[rr * 16 + u * 4 + 3] = h2{(_Float16)v1.z, (_Float16)v1.w};
        }
    }

    // poller mapping (tid<192): remote slices only; LDS addr == word index
    const int si  = tid >> 6;                 // 0..2
    const int qs  = si + (si >= s);           // skip own slice
    const int prw = qs * 64 + (tid & 63);

    if (tid < 256) hl[0][tid] = 0;            // h = 0 for step 0

    float cval = 0.0f;                        // cell state (lanes c<4: row g*4+c)

    for (int st = 0; st < TOT_STEPS; ++st) {
        const int t   = st & (T_STEPS - 1);
        const int buf = st & 1;

        // xproj word for this act-lane's row (in flight during the step)
        u32 xw = 0;
        if (c < 4) xw = xp16[((size_t)t * BATCH + b) * 256 + s * 64 + g * 2 + (c >> 1)];

        // first probe of the remote word, in flight during own-slice dot
        const u64* pp = hx + ((size_t)buf * BATCH + b) * 256 + prw;
        u64 pv = 0;
        if (tid < 192) pv = ld_llc(pp);

        __syncthreads();   // bar1: last step's bypass (own-slice h) published

        // ---- own-slice dot: 1 read, 16 dot2 (hides part of the LLC RT) ----
        float a0 = 0.f, a1 = 0.f, a2 = 0.f, a3 = 0.f;
        {
            float4 rv = *(const float4*)&hl[buf][s * 64 + c * 4];
            h2 x0 = bch2(rv.x), x1 = bch2(rv.y), x2 = bch2(rv.z), x3 = bch2(rv.w);
            a0 = dot2f(w2[ 0], x0, a0); a0 = dot2f(w2[ 1], x1, a0);
            a0 = dot2f(w2[ 2], x2, a0); a0 = dot2f(w2[ 3], x3, a0);
            a1 = dot2f(w2[16], x0, a1); a1 = dot2f(w2[17], x1, a1);
            a1 = dot2f(w2[18], x2, a1); a1 = dot2f(w2[19], x3, a1);
            a2 = dot2f(w2[32], x0, a2); a2 = dot2f(w2[33], x1, a2);
            a2 = dot2f(w2[34], x2, a2); a2 = dot2f(w2[35], x3, a2);
            a3 = dot2f(w2[48], x0, a3); a3 = dot2f(w2[49], x1, a3);
            a3 = dot2f(w2[50], x2, a3); a3 = dot2f(w2[51], x3, a3);
        }

        // ---- detect + stage the remote slices ----
        if (tid < 192) {
            u64 v = pv;
            int spin = 0;
            while ((u32)(v >> 32) != (u32)st) {
                v = ld_llc(pp);
                if (++spin > (1 << 16)) break;        // safety bailout
                if (spin > 64) __builtin_amdgcn_s_sleep(1);
            }
            hl[buf][prw] = (u32)v;
        }
        __syncthreads();   // bar2: remote h staged

        // ---- remote dot: 3 reads x 16 dot2 ----
        #pragma unroll
        for (int u = 1; u < 4; ++u) {
            float4 rv = *(const float4*)&hl[buf][((s + u) & 3) * 64 + c * 4];
            h2 x0 = bch2(rv.x), x1 = bch2(rv.y), x2 = bch2(rv.z), x3 = bch2(rv.w);
            a0 = dot2f(w2[     u*4+0], x0, a0); a0 = dot2f(w2[     u*4+1], x1, a0);
            a0 = dot2f(w2[     u*4+2], x2, a0); a0 = dot2f(w2[     u*4+3], x3, a0);
            a1 = dot2f(w2[16 + u*4+0], x0, a1); a1 = dot2f(w2[16 + u*4+1], x1, a1);
            a1 = dot2f(w2[16 + u*4+2], x2, a1); a1 = dot2f(w2[16 + u*4+3], x3, a1);
            a2 = dot2f(w2[32 + u*4+0], x0, a2); a2 = dot2f(w2[32 + u*4+1], x1, a2);
            a2 = dot2f(w2[32 + u*4+2], x2, a2); a2 = dot2f(w2[32 + u*4+3], x3, a2);
            a3 = dot2f(w2[48 + u*4+0], x0, a3); a3 = dot2f(w2[48 + u*4+1], x1, a3);
            a3 = dot2f(w2[48 + u*4+2], x2, a3); a3 = dot2f(w2[48 + u*4+3], x3, a3);
        }

        // 16-lane reduce, pure DPP; lanes c<4 get full sums
        a0 = reduce16(a0);
        a1 = reduce16(a1);
        a2 = reduce16(a2);
        a3 = reduce16(a3);

        float hf = 0.0f;
        if (c < 4) {
            float p = (c == 0) ? a0 : (c == 1) ? a1 : (c == 2) ? a2 : a3;
            h2 xp = bch2u(xw);
            float gg = p + (float)((c & 1) ? xp.y : xp.x);
            gg = fminf(fmaxf(gg, -30.0f), 30.0f);
            float sg = 1.0f / (1.0f + __expf(-gg));     // sigmoid
            float e2 = __expf(2.0f * gg);               // tanh(g)
            float ch = (e2 - 1.0f) / (e2 + 1.0f);
            cval = cval * sg + ch * sg;
            float ca = fminf(fmaxf(cval, -15.0f), 15.0f);
            float e3 = __expf(2.0f * ca);               // tanh(c)
            hf = ((e3 - 1.0f) / (e3 + 1.0f)) * sg;
        }
        // pack row pair: lanes (c=0,c=1) and (c=2,c=3) hold consecutive rows
        float hfo = __shfl_down(hf, 1);
        if (c == 0 || c == 2) {
            const int w = s * 64 + g * 2 + (c >> 1);
            u32 pk = packh2(hf, hfo);
            st_llc(hx + ((size_t)((st + 1) & 1) * BATCH + b) * 256 + w,
                   (u64)pk | ((u64)(u32)(st + 1) << 32));
            hl[buf ^ 1][w] = pk;           // local bypass for own slice
        }
        // no trailing barrier: bypass writes hl[buf^1]; next step's bar1
        // orders them before any read (next pollers write only remote words).
    }
}

// -------------------------------------------------------------------------
// Kernel 3: output = h_final @ out_w.T + out_b. Final h in hx buffer 0
// (TOT_STEPS even), 2 fp16 per word's low 32 bits.
// -------------------------------------------------------------------------
__global__ __launch_bounds__(256) void out_kernel(
    const u64* __restrict__ hx,
    const float* __restrict__ out_w,
    const float* __restrict__ out_b,
    float* __restrict__ out)
{
    const int b  = blockIdx.x;    // 64
    const int jt = threadIdx.x;   // 256
    __shared__ float hrow[512];

    {
        u64 v = hx[(size_t)b * 256 + jt];
        h2 pr = bch2u((u32)v);
        hrow[2 * jt]     = (float)pr.x;
        hrow[2 * jt + 1] = (float)pr.y;
    }
    __syncthreads();

    float acc = out_b[jt];
    const float* wr = out_w + (size_t)jt * HID;
    #pragma unroll 8
    for (int k = 0; k < HID; ++k)
        acc += hrow[k] * wr[k];
    out[(size_t)b * IN_SZ + jt] = acc;
}

// -------------------------------------------------------------------------
extern "C" void kernel_launch(void* const* d_in, const int* in_sizes, int n_in,
                              void* d_out, int out_size, void* d_ws, size_t ws_size,
                              hipStream_t stream)
{
    const float* input  = (const float*)d_in[0];
    const float* gate_w = (const float*)d_in[1];
    const float* gate_b = (const float*)d_in[2];
    const float* out_w  = (const float*)d_in[3];
    const float* out_b  = (const float*)d_in[4];
    float* out = (float*)d_out;

    // ws layout: Xproj fp16-packed (128 MB) | hx [2][64][256] u64 (256 KB)
    u32* xp16 = (u32*)d_ws;
    const size_t xbytes = (size_t)T_STEPS * BATCH * 256 * sizeof(u32);
    u64* hx = (u64*)((char*)d_ws + xbytes);

    // zero the exchange every launch: tag 0 == initial h = 0; graph replays
    // must never see stale tags.
    (void)hipMemsetAsync(hx, 0, (size_t)2 * BATCH * 256 * sizeof(u64), stream);

    dim3 g1(8, 64);
    xproj_kernel<<<g1, 256, 0, stream>>>(input, gate_w, gate_b, xp16);
    lstm_kernel<<<256, 512, 0, stream>>>(gate_w, xp16, hx);
    out_kernel<<<64, 256, 0, stream>>>(hx, out_w, out_b, out);
}